// Round 3
// baseline (923.978 us; speedup 1.0000x reference)
//
#include <hip/hip_runtime.h>

// Problem constants: N=50000, D=64, R=3, E=800000
#define N_NODES 50000
#define DFEAT   64
#define NREL    3
#define NEDGE   800000
#define OUT_COLS 256                 // (R+1)*D floats per output row
#define BROWS   64                   // rows per bucket
#define NBUCK   ((N_NODES + BROWS - 1) / BROWS)   // 782
#define TB      (NREL * NBUCK)       // 2346
#define SCAT_BLOCKS 200

// ---------------- bucketed path ----------------

__global__ void zero_counts_kernel(int* __restrict__ counts) {
    int i = blockIdx.x * 256 + threadIdx.x;
    if (i < TB) counts[i] = 0;
}

// grid (128, NREL), block 256. LDS histogram per block, flush with atomics.
__global__ void count_kernel(const int* __restrict__ rows, int* __restrict__ counts) {
    __shared__ int hist[NBUCK];
    int rel = blockIdx.y;
    int tid = threadIdx.x;
    for (int i = tid; i < NBUCK; i += 256) hist[i] = 0;
    __syncthreads();
    const int* rr = rows + rel * NEDGE;
    for (int e = blockIdx.x * 256 + tid; e < NEDGE; e += gridDim.x * 256)
        atomicAdd(&hist[rr[e] >> 6], 1);
    __syncthreads();
    for (int i = tid; i < NBUCK; i += 256)
        if (hist[i]) atomicAdd(&counts[rel * NBUCK + i], hist[i]);
}

// single block of 256. counts[TB] -> offsets[TB+1]; cursor = copy of offsets.
__global__ void scan_kernel(const int* __restrict__ counts,
                            int* __restrict__ offsets,
                            int* __restrict__ cursor) {
    __shared__ int part[256];
    const int PER = (TB + 255) / 256;   // 10
    int t = threadIdx.x;
    int base = t * PER;
    int loc[PER];
    int s = 0;
    for (int k = 0; k < PER; ++k) {
        int idx = base + k;
        int v = (idx < TB) ? counts[idx] : 0;
        loc[k] = s;
        s += v;
    }
    part[t] = s;
    __syncthreads();
    for (int off = 1; off < 256; off <<= 1) {
        int v = 0;
        if (t >= off) v = part[t - off];
        __syncthreads();
        if (t >= off) part[t] += v;
        __syncthreads();
    }
    int excl = (t == 0) ? 0 : part[t - 1];
    for (int k = 0; k < PER; ++k) {
        int idx = base + k;
        if (idx < TB) {
            int v = excl + loc[k];
            offsets[idx] = v;
            cursor[idx]  = v;
        }
    }
    if (t == 255) offsets[TB] = part[255];
}

// grid (SCAT_BLOCKS, NREL), block 256. Two-pass block reservation, then scatter
// packed records {(col<<6)|rowlocal, val_bits} into bucket-contiguous ws.
__global__ void scatter_kernel(const int* __restrict__ rows,
                               const int* __restrict__ cols,
                               const float* __restrict__ vals,
                               int* __restrict__ cursor,
                               uint2* __restrict__ recs) {
    __shared__ int hist[NBUCK];
    __shared__ int basei[NBUCK];
    int rel = blockIdx.y;
    int tid = threadIdx.x;
    for (int i = tid; i < NBUCK; i += 256) hist[i] = 0;
    __syncthreads();
    const int*   rr = rows + rel * NEDGE;
    const int*   cc = cols + rel * NEDGE;
    const float* vv = vals + rel * NEDGE;
    const int chunk = (NEDGE + gridDim.x - 1) / gridDim.x;
    int e0 = blockIdx.x * chunk;
    int e1 = min(e0 + chunk, NEDGE);
    for (int e = e0 + tid; e < e1; e += 256)
        atomicAdd(&hist[rr[e] >> 6], 1);
    __syncthreads();
    for (int i = tid; i < NBUCK; i += 256) {
        int c = hist[i];
        basei[i] = (c > 0) ? atomicAdd(&cursor[rel * NBUCK + i], c) : 0;
        hist[i] = 0;
    }
    __syncthreads();
    for (int e = e0 + tid; e < e1; e += 256) {
        int row = rr[e];
        int bk = row >> 6;
        int pos = basei[bk] + atomicAdd(&hist[bk], 1);
        recs[pos] = make_uint2(((unsigned)cc[e] << 6) | (unsigned)(row & 63),
                               __float_as_uint(vv[e]));
    }
}

// grid TB blocks, block 256 (4 waves). Each wave owns a contiguous sub-range
// of the bucket's records. Records are batch-loaded 64-at-a-time (coalesced)
// into a per-wave LDS slot, then replayed via broadcast ds_read with the
// gather loop unrolled x8 for deep memory-level parallelism.
__global__ void accum_kernel(const float* __restrict__ x,
                             const int* __restrict__ offsets,
                             const uint2* __restrict__ recs,
                             float* __restrict__ out) {
    __shared__ float acc[BROWS * DFEAT];     // 16 KB
    __shared__ uint2 rstage[4 * 64];         // 2 KB, 64 recs per wave
    int b    = blockIdx.x;
    int rel  = b / NBUCK;
    int buck = b % NBUCK;
    int tid  = threadIdx.x;
    float4* acc4 = (float4*)acc;
    for (int i = tid; i < BROWS * DFEAT / 4; i += 256)
        acc4[i] = make_float4(0.f, 0.f, 0.f, 0.f);
    __syncthreads();

    int start = offsets[b], end = offsets[b + 1];
    int lane = tid & 63, wave = tid >> 6;

    // contiguous per-wave sub-range
    int total = end - start;
    int per   = (total + 3) >> 2;
    int ws    = start + wave * per;
    int we    = min(ws + per, end);
    uint2* myst = &rstage[wave * 64];

    int j = ws;
    for (; j + 64 <= we; j += 64) {
        myst[lane] = recs[j + lane];          // coalesced 512B per wave
        __builtin_amdgcn_s_waitcnt(0);        // drain lgkm+vm before replay
        #pragma unroll 8
        for (int k = 0; k < 64; ++k) {
            uint2 rk = myst[k];               // broadcast ds_read
            float xv = x[(rk.x >> 6) * DFEAT + lane];
            atomicAdd(&acc[(rk.x & 63) * DFEAT + lane],
                      __uint_as_float(rk.y) * xv);
        }
    }
    // remainder (< 64 records): broadcast global reads
    for (; j < we; ++j) {
        uint2 rk = recs[j];
        float xv = x[(rk.x >> 6) * DFEAT + lane];
        atomicAdd(&acc[(rk.x & 63) * DFEAT + lane],
                  __uint_as_float(rk.y) * xv);
    }
    __syncthreads();

    int row0 = buck * BROWS;
    for (int i = tid; i < BROWS * DFEAT / 4; i += 256) {
        int rowl = i >> 4;     // 16 float4 per row
        int c4   = i & 15;
        int row  = row0 + rowl;
        if (row < N_NODES)
            ((float4*)out)[row * (OUT_COLS / 4) + rel * 16 + c4] = acc4[i];
    }
}

// out[:, 192:256] = x
__global__ void copyx_kernel(const float4* __restrict__ x4, float4* __restrict__ out4) {
    int i = blockIdx.x * 256 + threadIdx.x;
    if (i >= N_NODES * 16) return;
    int row = i >> 4, c = i & 15;
    out4[row * (OUT_COLS / 4) + 48 + c] = x4[i];
}

// ---------------- fallback path (no workspace) ----------------

__global__ void init_out_kernel(const float4* __restrict__ x4, float4* __restrict__ out4) {
    int j = blockIdx.x * blockDim.x + threadIdx.x;
    if (j >= N_NODES * 64) return;
    int row = j >> 6, c = j & 63;
    float4 v;
    if (c < 48) v = make_float4(0.f, 0.f, 0.f, 0.f);
    else        v = x4[row * 16 + (c - 48)];
    out4[j] = v;
}

__global__ void scatter_spmm_kernel(const float* __restrict__ x,
                                    const int* __restrict__ rows,
                                    const int* __restrict__ cols,
                                    const float* __restrict__ vals,
                                    float* __restrict__ out) {
    int idx = blockIdx.x * blockDim.x + threadIdx.x;
    int e = idx >> 4, sub = idx & 15;
    if (e >= NEDGE) return;
    int r = blockIdx.y;
    long base = (long)r * NEDGE + e;
    int row = rows[base], col = cols[base];
    float val = vals[base];
    const float4 xv = *reinterpret_cast<const float4*>(x + (long)col * DFEAT + sub * 4);
    float* o = out + (long)row * OUT_COLS + r * DFEAT + sub * 4;
    atomicAdd(o + 0, val * xv.x);
    atomicAdd(o + 1, val * xv.y);
    atomicAdd(o + 2, val * xv.z);
    atomicAdd(o + 3, val * xv.w);
}

// ---------------- launch ----------------

extern "C" void kernel_launch(void* const* d_in, const int* in_sizes, int n_in,
                              void* d_out, int out_size, void* d_ws, size_t ws_size,
                              hipStream_t stream) {
    const float* x         = (const float*)d_in[0];
    const int*   edge_rows = (const int*)d_in[1];
    const int*   edge_cols = (const int*)d_in[2];
    const float* edge_vals = (const float*)d_in[3];
    float* out = (float*)d_out;

    const size_t REC_OFF = 32768;
    const size_t NEED = REC_OFF + (size_t)NREL * NEDGE * sizeof(uint2);  // ~19.2 MB

    if (ws_size >= NEED) {
        int*   counts  = (int*)d_ws;            // TB ints
        int*   offsets = counts + TB;           // TB+1 ints
        int*   cursor  = offsets + TB + 1;      // TB ints  (< 32 KB total)
        uint2* recs    = (uint2*)((char*)d_ws + REC_OFF);

        zero_counts_kernel<<<(TB + 255) / 256, 256, 0, stream>>>(counts);
        count_kernel<<<dim3(128, NREL), 256, 0, stream>>>(edge_rows, counts);
        scan_kernel<<<1, 256, 0, stream>>>(counts, offsets, cursor);
        scatter_kernel<<<dim3(SCAT_BLOCKS, NREL), 256, 0, stream>>>(
            edge_rows, edge_cols, edge_vals, cursor, recs);
        accum_kernel<<<TB, 256, 0, stream>>>(x, offsets, recs, out);
        copyx_kernel<<<(N_NODES * 16 + 255) / 256, 256, 0, stream>>>(
            (const float4*)x, (float4*)out);
    } else {
        // Fallback: global-atomic scatter (correct, slower)
        {
            int total = N_NODES * 64;
            init_out_kernel<<<(total + 255) / 256, 256, 0, stream>>>(
                (const float4*)x, (float4*)out);
        }
        {
            int threads_per_rel = NEDGE * 16;
            int blocks = (threads_per_rel + 255) / 256;
            dim3 grid(blocks, NREL);
            scatter_spmm_kernel<<<grid, 256, 0, stream>>>(
                x, edge_rows, edge_cols, edge_vals, out);
        }
    }
}